// Round 3
// baseline (55.173 us; speedup 1.0000x reference)
//
#include <hip/hip_runtime.h>
#include <stdint.h>

// CachedCompressedLinear: out[b][o] = sum_k x[b][k] * ((wq[o][k]-128)*scale) + bias[o]
// x: [16][4096] f32, wq: [11008][4096] int32 codes in [0,255], scale f32, bias[11008] f32.
//
// R1/R2 pinned at 49us (3.67 TB/s): every w-load was 16-way row-divergent at
// 16KB stride (L1 set-aliasing + 16 lines/instr). R3: canonical LDS-staged
// structure — wave-contiguous 1KB global reads via global_load_lds(16B),
// double-buffered 32KB chunks, XOR-swizzled LDS (linear dest + inverse-swz
// source + swz read, rule #21) so MFMA fragment reads are ~conflict-free.

constexpr int IN_F  = 4096;
constexpr int OUT_F = 11008;
constexpr int NWAVES = 8;
constexpr int BK = 512;                    // k per chunk (ints)
constexpr int NCHUNK = IN_F / BK;          // 8
constexpr int ROW_BYTES = BK * 4;          // 2048 bytes per row per chunk
constexpr int CHUNK_BYTES = 16 * ROW_BYTES;// 32768

typedef _Float16 f16x8 __attribute__((ext_vector_type(8)));
typedef float    f32x4 __attribute__((ext_vector_type(4)));

__device__ inline f16x8 cvt_codes(int4 a, int4 b) {
    f16x8 r;   // codes in [0,255]; (c-128) exact in f16
    r[0] = (_Float16)(a.x - 128); r[1] = (_Float16)(a.y - 128);
    r[2] = (_Float16)(a.z - 128); r[3] = (_Float16)(a.w - 128);
    r[4] = (_Float16)(b.x - 128); r[5] = (_Float16)(b.y - 128);
    r[6] = (_Float16)(b.z - 128); r[7] = (_Float16)(b.w - 128);
    return r;
}

__global__ __launch_bounds__(NWAVES * 64, 4)
void qlinear_mfma(const float* __restrict__ x,
                  const int*   __restrict__ wq,
                  const float* __restrict__ scale,
                  const float* __restrict__ bias,
                  float*       __restrict__ out)
{
    __shared__ __align__(16) char smem[2 * CHUNK_BYTES];   // 64 KB w double-buffer
    __shared__ f32x4 red[NWAVES][64];                      // 8 KB reduce

    const int tid  = threadIdx.x;
    const int lane = tid & 63;
    const int wave = tid >> 6;
    const int obase = blockIdx.x * 16;

    const int ncol = lane & 15;   // B col (o_local) == A row (batch)
    const int kgrp = lane >> 4;   // 0..3

    // ---- hoist x A-fragments (one-time; L2-resident) ----
    // frag f = c*2 + jj covers k = c*512 + (wave*2+jj)*32 + kgrp*8 + [0,8)
    f16x8 a[2 * NCHUNK];
    {
        const float* xp = x + (size_t)ncol * IN_F;
        #pragma unroll
        for (int f = 0; f < 2 * NCHUNK; ++f) {
            const int c  = f >> 1, jj = f & 1;
            const int kb = c * BK + (wave * 2 + jj) * 32 + kgrp * 8;
            const float4 xa = *reinterpret_cast<const float4*>(xp + kb);
            const float4 xb = *reinterpret_cast<const float4*>(xp + kb + 4);
            f16x8 t;
            t[0] = (_Float16)xa.x; t[1] = (_Float16)xa.y;
            t[2] = (_Float16)xa.z; t[3] = (_Float16)xa.w;
            t[4] = (_Float16)xb.x; t[5] = (_Float16)xb.y;
            t[6] = (_Float16)xb.z; t[7] = (_Float16)xb.w;
            a[f] = t;
        }
    }

    // ---- staging: wave-contiguous 1KB reads, linear LDS dest,
    //      inverse-swizzled global source (swz is wave-uniform) ----
    const char* wq_bytes = reinterpret_cast<const char*>(wq);
    auto stage = [&](int c, int buf) {
        #pragma unroll
        for (int p = 0; p < 4; ++p) {
            const int row = p * 4 + (wave >> 1);          // 0..15
            const int within = (((wave & 1) * 1024) + lane * 16) ^ ((row & 7) << 4);
            const char* src = wq_bytes + (size_t)(obase + row) * (IN_F * 4)
                                       + (size_t)c * ROW_BYTES + within;
            char* dst = smem + buf * CHUNK_BYTES + p * 8192 + wave * 1024 + lane * 16;
            __builtin_amdgcn_global_load_lds(
                (const __attribute__((address_space(1))) void*)src,
                (__attribute__((address_space(3))) void*)dst, 16, 0, 0);
        }
    };

    stage(0, 0);
    __syncthreads();   // drains vmcnt(0): chunk 0 resident

    f32x4 acc = {0.f, 0.f, 0.f, 0.f};
    const int swz = (ncol & 7) << 4;

    for (int c = 0; c < NCHUNK; ++c) {
        const int buf = c & 1;
        if (c + 1 < NCHUNK) stage(c + 1, buf ^ 1);   // async prefetch

        const char* rowbase = smem + buf * CHUNK_BYTES + ncol * ROW_BYTES;
        #pragma unroll
        for (int jj = 0; jj < 2; ++jj) {
            const int kb = wave * 2 + jj;                 // k-block within chunk
            const int lo = kgrp * 32 + kb * 128;          // logical byte offset
            const int4 w0 = *reinterpret_cast<const int4*>(rowbase + ((lo)      ^ swz));
            const int4 w1 = *reinterpret_cast<const int4*>(rowbase + ((lo + 16) ^ swz));
            const f16x8 bf = cvt_codes(w0, w1);
            acc = __builtin_amdgcn_mfma_f32_16x16x32_f16(a[c * 2 + jj], bf, acc, 0, 0, 0);
        }
        __syncthreads();   // stage(c+1) landed; buf safe to overwrite next iter
    }

    // ---- reduce 8 per-wave partials (disjoint k subsets) ----
    red[wave][lane] = acc;
    __syncthreads();

    if (wave == 0) {
        f32x4 s = red[0][lane];
        #pragma unroll
        for (int w = 1; w < NWAVES; ++w) s += red[w][lane];

        const float sc = scale[0];
        const float bo = bias[obase + ncol];
        const int   brow = kgrp * 4;   // C/D: col=lane&15 -> o, row=(lane>>4)*4+r -> batch
        #pragma unroll
        for (int r = 0; r < 4; ++r)
            out[(size_t)(brow + r) * OUT_F + obase + ncol] = s[r] * sc + bo;
    }
}

extern "C" void kernel_launch(void* const* d_in, const int* in_sizes, int n_in,
                              void* d_out, int out_size, void* d_ws, size_t ws_size,
                              hipStream_t stream) {
    const float* x     = (const float*)d_in[0];
    const int*   wq    = (const int*)d_in[1];
    const float* scale = (const float*)d_in[2];
    const float* bias  = (const float*)d_in[3];
    float*       out   = (float*)d_out;

    dim3 grid(OUT_F / 16);        // 688 o-tiles
    dim3 block(NWAVES * 64);      // 512 threads
    qlinear_mfma<<<grid, block, 0, stream>>>(x, wq, scale, bias, out);
}